// Round 14
// baseline (477.647 us; speedup 1.0000x reference)
//
#include <hip/hip_runtime.h>
#include <hip/hip_bf16.h>

// Problem constants (B=1)
#define CL 2048   // sequence length
#define CD 1024   // hidden
#define CH 16     // heads
#define CHD 64    // head dim
#define NEGS -1e30f

typedef __attribute__((ext_vector_type(8))) short short8;  // 8 x bf16 frag
typedef __attribute__((ext_vector_type(4))) float f32x4;
// One row of scores: 32 regs, static indices everywhere.
typedef __attribute__((ext_vector_type(32))) float f32x32;

// DPP wave reductions (R16; measured R9 ~-8us, kept: strictly better).
template <int CTRL>
__device__ __forceinline__ float dpp_add_step(float x) {
  int v = __builtin_amdgcn_update_dpp(0, __builtin_bit_cast(int, x),
                                      CTRL, 0xf, 0xf, true);
  return x + __builtin_bit_cast(float, v);
}
template <int CTRL>
__device__ __forceinline__ float dpp_max_step(float x) {
  int v = __builtin_amdgcn_update_dpp((int)0xff800000, __builtin_bit_cast(int, x),
                                      CTRL, 0xf, 0xf, false);
  return fmaxf(x, __builtin_bit_cast(float, v));
}
__device__ __forceinline__ float wave_sum(float x) {
  x = dpp_add_step<0x111>(x);  // row_shr:1
  x = dpp_add_step<0x112>(x);  // row_shr:2
  x = dpp_add_step<0x114>(x);  // row_shr:4
  x = dpp_add_step<0x118>(x);  // row_shr:8
  x = dpp_add_step<0x142>(x);  // row_bcast:15
  x = dpp_add_step<0x143>(x);  // row_bcast:31
  return __builtin_bit_cast(float,
      __builtin_amdgcn_readlane(__builtin_bit_cast(int, x), 63));
}
__device__ __forceinline__ float wave_max(float x) {
  x = dpp_max_step<0x111>(x);
  x = dpp_max_step<0x112>(x);
  x = dpp_max_step<0x114>(x);
  x = dpp_max_step<0x118>(x);
  x = dpp_max_step<0x142>(x);
  x = dpp_max_step<0x143>(x);
  return __builtin_bit_cast(float,
      __builtin_amdgcn_readlane(__builtin_bit_cast(int, x), 63));
}

__device__ __forceinline__ void split1(float v, short& h, short& l) {
  __hip_bfloat16 bh = __float2bfloat16(v);
  __hip_bfloat16 bl = __float2bfloat16(v - __bfloat162float(bh));
  h = __builtin_bit_cast(short, bh);
  l = __builtin_bit_cast(short, bl);
}
__device__ __forceinline__ unsigned short bf16_bits(float v) {
  __hip_bfloat16 b = __float2bfloat16(v);
  return (unsigned short)__builtin_bit_cast(short, b);
}

// ---- depth-5 tree helpers over f32x32 (one-shot; unguarded on purpose:
// relu MUST zero the causally-masked elems for the Ptile write) ----
__device__ __forceinline__ float tree_sum_valid(const f32x32& s) {
  float t[8];
#pragma unroll
  for (int i = 0; i < 8; i++) {
    const float a = s[i]      > -1e29f ? s[i]      : 0.f;
    const float b = s[i + 8]  > -1e29f ? s[i + 8]  : 0.f;
    const float c = s[i + 16] > -1e29f ? s[i + 16] : 0.f;
    const float d = s[i + 24] > -1e29f ? s[i + 24] : 0.f;
    t[i] = (a + b) + (c + d);
  }
#pragma unroll
  for (int i = 0; i < 4; i++) t[i] += t[i + 4];
  t[0] += t[2]; t[1] += t[3];
  return t[0] + t[1];
}
__device__ __forceinline__ float tree_max(const f32x32& s) {
  float t[8];
#pragma unroll
  for (int i = 0; i < 8; i++)
    t[i] = fmaxf(fmaxf(s[i], s[i + 8]), fmaxf(s[i + 16], s[i + 24]));
#pragma unroll
  for (int i = 0; i < 4; i++) t[i] = fmaxf(t[i], t[i + 4]);
  return fmaxf(fmaxf(t[0], t[2]), fmaxf(t[1], t[3]));
}
__device__ __forceinline__ float relu_store_sum(f32x32& s, float ts_) {
  float t[8];
#pragma unroll
  for (int i = 0; i < 8; i++) {
    float a = s[i] - ts_;      a = a > 0.f ? a : 0.f;
    float b = s[i + 8] - ts_;  b = b > 0.f ? b : 0.f;
    float c = s[i + 16] - ts_; c = c > 0.f ? c : 0.f;
    float d = s[i + 24] - ts_; d = d > 0.f ? d : 0.f;
    s[i] = a; s[i + 8] = b; s[i + 16] = c; s[i + 24] = d;
    t[i] = (a + b) + (c + d);
  }
#pragma unroll
  for (int i = 0; i < 4; i++) t[i] += t[i + 4];
  t[0] += t[2]; t[1] += t[3];
  return t[0] + t[1];
}

// R19/R20 fused 2-row Michelot (measured R12: attn 318->235us with the
// 32-row/2-per-wave structure). Ballot count on scalar pipe; it-invariant
// wave-uniform causal guards; per-row gated tau/cnt updates; freeze-stable.
__device__ __forceinline__ void entmax_pair(f32x32& s0, f32x32& s1,
                                            int g0, int g1,
                                            float& inv0, float& inv1) {
  const float ss0 = wave_sum(tree_sum_valid(s0));
  const float m0  = wave_max(tree_max(s0));
  const float ss1 = wave_sum(tree_sum_valid(s1));
  const float m1  = wave_max(tree_max(s1));
  float tau0 = m0 - 1.000001f, tau1 = m1 - 1.000001f;
  int cnt0 = 0, cnt1 = 0;
  for (int it = 0; it < 64; it++) {
    float sum0 = 0.f, sum1 = 0.f;
    int c0 = 0, c1 = 0;
#pragma unroll
    for (int jt = 0; jt < 8; jt++) {
      if (jt * 256 <= g0) {             // wave-uniform causal guard (row 0)
#pragma unroll
        for (int tt = 0; tt < 4; tt++) {
          const float a = s0[jt * 4 + tt];
          const bool pr = a > tau0;
          sum0 += pr ? a : 0.f;
          c0 += (int)__popcll(__ballot(pr));
        }
      }
      if (jt * 256 <= g1) {             // wave-uniform causal guard (row 1)
#pragma unroll
        for (int tt = 0; tt < 4; tt++) {
          const float a = s1[jt * 4 + tt];
          const bool pr = a > tau1;
          sum1 += pr ? a : 0.f;
          c1 += (int)__popcll(__ballot(pr));
        }
      }
    }
    const float cs0 = wave_sum(sum0);   // two independent DPP chains (ILP)
    const float cs1 = wave_sum(sum1);
    const bool st0 = (c0 == cnt0), st1 = (c1 == cnt1);
    if (st0 && st1) break;
    if (!st0) { cnt0 = c0; tau0 = (cs0 - 1.f) / (float)c0; }
    if (!st1) { cnt1 = c1; tau1 = (cs1 - 1.f) / (float)c1; }
  }
  const float ts0 = (ss0 - 1.f) / (float)cnt0;
  const float ts1 = (ss1 - 1.f) / (float)cnt1;
  inv0 = 1.f / (wave_sum(relu_store_sum(s0, ts0)) + 1e-10f);
  inv1 = 1.f / (wave_sum(relu_store_sum(s1, ts1)) + 1e-10f);
}

// One fused split kernel: fp32 -> bf16 hi/lo planes for x and 4 weights.
__global__ __launch_bounds__(256) void split_all(
    const float* __restrict__ x,  const float* __restrict__ wq,
    const float* __restrict__ wk, const float* __restrict__ wv,
    const float* __restrict__ wo,
    short* __restrict__ xh,  short* __restrict__ xl,
    short* __restrict__ wqh, short* __restrict__ wql,
    short* __restrict__ wkh, short* __restrict__ wkl,
    short* __restrict__ wvh, short* __restrict__ wvl,
    short* __restrict__ woh, short* __restrict__ wol) {
  const int b = blockIdx.x;
  const float* src; short *dh, *dl; int i0;
  if      (b < 2048) { src = x;  dh = xh;  dl = xl;  i0 = b; }
  else if (b < 3072) { src = wq; dh = wqh; dl = wql; i0 = b - 2048; }
  else if (b < 4096) { src = wk; dh = wkh; dl = wkl; i0 = b - 3072; }
  else if (b < 5120) { src = wv; dh = wvh; dl = wvl; i0 = b - 4096; }
  else               { src = wo; dh = woh; dl = wol; i0 = b - 5120; }
  const int i = i0 * 256 + threadIdx.x;
  const float4 v = reinterpret_cast<const float4*>(src)[i];
  const float vv[4] = {v.x, v.y, v.z, v.w};
  short hh[4], ll[4];
#pragma unroll
  for (int e = 0; e < 4; e++) split1(vv[e], hh[e], ll[e]);
  reinterpret_cast<short4*>(dh)[i] = make_short4(hh[0], hh[1], hh[2], hh[3]);
  reinterpret_cast<short4*>(dl)[i] = make_short4(ll[0], ll[1], ll[2], ll[3]);
}

// C[2048,1024] = (Ah+Al) * (B?h+B?l)^T via 3-term split-bf16 MFMA.
// 128x128 tile/WG. R21 (measured win, ~-58us vs BK=32): BK=64 — two 32-K
// sub-steps per barrier pair. LDS 64KB (2 blocks/CU). Numerics bit-identical.
// Lane-linear staging: LDS off = i*1024 + lane*16; global row = i*8+(lane>>3),
// chunk = (lane&7)*8.
__global__ __launch_bounds__(256, 2) void gemm128_split(
    const short* __restrict__ Ah, const short* __restrict__ Al,
    const short* __restrict__ B0h, const short* __restrict__ B0l,
    const short* __restrict__ B1h, const short* __restrict__ B1l,
    const short* __restrict__ B2h, const short* __restrict__ B2l,
    short* __restrict__ O0h, short* __restrict__ O0l,
    short* __restrict__ O1h, short* __restrict__ O1l,
    short* __restrict__ O2h, short* __restrict__ O2l,
    float* __restrict__ Cf, int fp32out) {
  __shared__ short AhS[128][64], AlS[128][64], BhS[128][64], BlS[128][64];
  const int tid = threadIdx.x, lane = tid & 63, wave = tid >> 6;
  const int l15 = lane & 15, quad = lane >> 4;
  const int sel = blockIdx.x >> 3, nb = blockIdx.x & 7;
  const short* Bh = sel == 0 ? B0h : (sel == 1 ? B1h : B2h);
  const short* Bl = sel == 0 ? B0l : (sel == 1 ? B1l : B2l);
  const int m0 = blockIdx.y * 128, n0 = nb * 128;
  const int wm = (wave >> 1) * 64, wn = (wave & 1) * 64;

  f32x4 acc[4][4];
#pragma unroll
  for (int i = 0; i < 4; i++)
#pragma unroll
    for (int j = 0; j < 4; j++) acc[i][j] = {0.f, 0.f, 0.f, 0.f};

  const short* gsrc = wave == 0 ? Ah : wave == 1 ? Al : wave == 2 ? Bh : Bl;
  short(*ldst)[64] = wave == 0 ? AhS : wave == 1 ? AlS : wave == 2 ? BhS : BlS;
  const int srow0 = (wave < 2) ? m0 : n0;
  const int sr = lane >> 3, skc = (lane & 7) * 8;  // row-in-8, 16B chunk

  for (int k0 = 0; k0 < CD; k0 += 64) {
    // 16 x global_load_lds_dwordx4: wave-uniform LDS base + lane*16.
#pragma unroll
    for (int i = 0; i < 16; i++) {
      const short* gp =
          gsrc + (size_t)(srow0 + i * 8 + sr) * CD + k0 + skc;
      __builtin_amdgcn_global_load_lds(
          (const __attribute__((address_space(1))) void*)gp,
          (__attribute__((address_space(3))) void*)((char*)&ldst[0][0] + i * 1024),
          16, 0, 0);
    }
    __syncthreads();
#pragma unroll
    for (int kb = 0; kb < 2; kb++) {
      short8 a_h[4], a_l[4], b_h[4], b_l[4];
#pragma unroll
      for (int i = 0; i < 4; i++) {
        a_h[i] = *reinterpret_cast<const short8*>(&AhS[wm + i * 16 + l15][kb * 32 + quad * 8]);
        a_l[i] = *reinterpret_cast<const short8*>(&AlS[wm + i * 16 + l15][kb * 32 + quad * 8]);
        b_h[i] = *reinterpret_cast<const short8*>(&BhS[wn + i * 16 + l15][kb * 32 + quad * 8]);
        b_l[i] = *reinterpret_cast<const short8*>(&BlS[wn + i * 16 + l15][kb * 32 + quad * 8]);
      }
#pragma unroll
      for (int im = 0; im < 4; im++)
#pragma unroll
        for (int in = 0; in < 4; in++) {
          acc[im][in] = __builtin_amdgcn_mfma_f32_16x16x32_bf16(a_h[im], b_l[in], acc[im][in], 0, 0, 0);
          acc[im][in] = __builtin_amdgcn_mfma_f32_16x16x32_bf16(a_l[im], b_h[in], acc[im][in], 0, 0, 0);
          acc[im][in] = __builtin_amdgcn_mfma_f32_16x16x32_bf16(a_h[im], b_h[in], acc[im][in], 0, 0, 0);
        }
    }
    __syncthreads();
  }

#pragma unroll
  for (int im = 0; im < 4; im++)
#pragma unroll
    for (int in = 0; in < 4; in++)
#pragma unroll
      for (int r = 0; r < 4; r++) {
        const int mr = m0 + wm + im * 16 + quad * 4 + r;
        const int nc = n0 + wn + in * 16 + l15;
        const float val = acc[im][in][r];
        if (fp32out) {
          Cf[(size_t)mr * CD + nc] = val;
        } else {
          short sh, sl;
          split1(val, sh, sl);
          if (sel == 0) {
            O0h[(size_t)mr * CD + nc] = sh; O0l[(size_t)mr * CD + nc] = sl;
          } else if (sel == 1) {
            O1h[(size_t)mr * CD + nc] = sh; O1l[(size_t)mr * CD + nc] = sl;
          } else {  // vT[dim][seq]
            O2h[(size_t)nc * CL + mr] = sh; O2l[(size_t)nc * CL + mr] = sl;
          }
        }
      }
}

// R22: attn32 merged back to ONE dispatch (R13 split cost ~13us imbalance;
// R12 measured the merged form at 235us) + register-prefetch pipelining:
// R13's split-read showed phases 1/3 are bound by the per-tile serial chain
// (K/V load latency -> MFMA -> barrier -> gather), nothing saturated.
// - Phase 1: K-frags for tile jt+1 prefetched into VGPRs during tile jt
//   (+32 regs; at 64/128 budget this is free) — load latency hides under
//   MFMA+scatter+barrier+gather instead of fronting each MFMA cluster.
// - Phase 3: both V-chunk loads issued BEFORE the Ptile barrier (independent
//   of LDS), consumed after — latency overlaps the barrier drain.
// Guards identical to consumers (wave-uniform); overrun extents unchanged.
__global__ __launch_bounds__(1024, 4) void attn32(
    const short* __restrict__ qh, const short* __restrict__ ql,
    const short* __restrict__ kh, const short* __restrict__ kl,
    const short* __restrict__ vhT, const short* __restrict__ vlT,
    short* __restrict__ oh, short* __restrict__ ol) {
  __shared__ float Stile[2][32][260];           // 66.6 KB
  __shared__ unsigned short Ptile[2][32][264];  // 33.8 KB
  __shared__ float Rtile[4][32][68];            // 34.8 KB partial PV
  __shared__ float invS[32];                    // total ~132 KB

  const int tid = threadIdx.x, lane = tid & 63, wave = tid >> 6;
  const int l15 = lane & 15, quad = lane >> 4;
  const int bx = blockIdx.x;
  const int qb = (bx & 1) ? (63 - (bx >> 1)) : (bx >> 1);  // heavy+light mix
  const int h = blockIdx.y, q0 = qb * 32, col0 = h * CHD;
  const int g0 = q0 + wave;                   // wave's row in group A (0..15)
  const int g1 = q0 + 16 + wave;              // wave's row in group B (16..31)
  const int ntiles = (q0 + 287) >> 8;         // 256-col tiles covering 0..q0+31
  const int rmax = q0 + 31;                   // last valid column in this block

  // A-frags for both row groups: m=l15, k=kb*32+quad*8+j [m89/m91 layout]
  short8 a0h[2], a0l[2], a1h[2], a1l[2];
  {
    const size_t qbA = (size_t)(q0 + l15) * CD + col0 + quad * 8;
    const size_t qbB = (size_t)(q0 + 16 + l15) * CD + col0 + quad * 8;
#pragma unroll
    for (int kb = 0; kb < 2; kb++) {
      a0h[kb] = *reinterpret_cast<const short8*>(qh + qbA + kb * 32);
      a0l[kb] = *reinterpret_cast<const short8*>(ql + qbA + kb * 32);
      a1h[kb] = *reinterpret_cast<const short8*>(qh + qbB + kb * 32);
      a1l[kb] = *reinterpret_cast<const short8*>(ql + qbB + kb * 32);
    }
  }

  f32x32 s0, s1;
#pragma unroll
  for (int t = 0; t < 32; t++) { s0[t] = NEGS; s1[t] = NEGS; }

  // ---- Phase 1: scores with K-frag register-prefetch pipeline ----
  short8 kfh[2], kfl[2];  // prefetched K frags for the CURRENT tile
  {
    // tile 0 (ntiles >= 1 always); guard matches consumer
    if (16 * wave <= rmax) {
      const size_t kbase = (size_t)(16 * wave + l15) * CD + col0 + quad * 8;
#pragma unroll
      for (int kb = 0; kb < 2; kb++) {
        kfh[kb] = *reinterpret_cast<const short8*>(kh + kbase + kb * 32);
        kfl[kb] = *reinterpret_cast<const short8*>(kl + kbase + kb * 32);
      }
    }
  }
#pragma unroll
  for (int jt = 0; jt < 8; jt++) {
    if (jt < ntiles) {                        // WG-uniform
      const int j0 = jt * 256;
      const int buf = jt & 1;
      const bool live = (j0 + 16 * wave <= rmax);  // wave-uniform
      short8 ch[2], cl[2];
      if (live) { ch[0] = kfh[0]; ch[1] = kfh[1]; cl[0] = kfl[0]; cl[1] = kfl[1]; }
      // prefetch NEXT tile's K frags (latency hides under this tile's work)
      if (jt + 1 < ntiles && (jt + 1) * 256 + 16 * wave <= rmax) {
        const size_t kb2 =
            (size_t)((jt + 1) * 256 + 16 * wave + l15) * CD + col0 + quad * 8;
#pragma unroll
        for (int kb = 0; kb < 2; kb++) {
          kfh[kb] = *reinterpret_cast<const short8*>(kh + kb2 + kb * 32);
          kfl[kb] = *reinterpret_cast<const short8*>(kl + kb2 + kb * 32);
        }
      }
      if (live) {
        f32x4 c0 = {0.f, 0.f, 0.f, 0.f};
        f32x4 c1 = {0.f, 0.f, 0.f, 0.f};
#pragma unroll
        for (int kb = 0; kb < 2; kb++) {
          c0 = __builtin_amdgcn_mfma_f32_16x16x32_bf16(a0l[kb], cl[kb], c0, 0, 0, 0);
          c0 = __builtin_amdgcn_mfma_f32_16x16x32_bf16(a0h[kb], cl[kb], c0, 0, 0, 0);
          c0 = __builtin_amdgcn_mfma_f32_16x16x32_bf16(a0l[kb], ch[kb], c0, 0, 0, 0);
          c0 = __builtin_amdgcn_mfma_f32_16x16x32_bf16(a0h[kb], ch[kb], c0, 0, 0, 0);
          c1 = __builtin_amdgcn_mfma_f32_16x16x32_bf16(a1l[kb], cl[kb], c1, 0, 0, 0);
          c1 = __builtin_amdgcn_mfma_f32_16x16x32_bf16(a1h[kb], cl[kb], c1, 0, 0, 0);
          c1 = __builtin_amdgcn_mfma_f32_16x16x32_bf16(a1l[kb], ch[kb], c1, 0, 0, 0);
          c1 = __builtin_amdgcn_mfma_f32_16x16x32_bf16(a1h[kb], ch[kb], c1, 0, 0, 0);
        }
        // C layout: col(seq) = 16*wave + l15, row(q) = quad*4 + r (+16 for B)
#pragma unroll
        for (int r = 0; r < 4; r++) {
          Stile[buf][quad * 4 + r][16 * wave + l15] = c0[r];
          Stile[buf][16 + quad * 4 + r][16 * wave + l15] = c1[r];
        }
      }
      __syncthreads();
      // Gather MY rows: lane ll owns cols j0 + 64*tt + ll (2-way = free)
#pragma unroll
      for (int tt = 0; tt < 4; tt++) {
        const int col = j0 + 64 * tt + lane;
        if (j0 + 64 * tt <= g0) {             // wave-uniform group-valid check
          const float v = Stile[buf][wave][64 * tt + lane] * 0.125f;  // exact
          s0[jt * 4 + tt] = (col <= g0) ? v : NEGS;
        }
        if (j0 + 64 * tt <= g1) {
          const float v = Stile[buf][wave + 16][64 * tt + lane] * 0.125f;
          s1[jt * 4 + tt] = (col <= g1) ? v : NEGS;
        }
      }
      // no trailing barrier: next scatter targets the other buffer
    }
  }

  // ---- Phase 2: fused 2-row Michelot per wave (32 rows in parallel) ----
  float inv0, inv1;
  entmax_pair(s0, s1, g0, g1, inv0, inv1);
  if (lane == 0) { invS[wave] = inv0; invS[wave + 16] = inv1; }

  // ---- Phase 3: P @ V (wave = (kgroup, dim-block); both row groups) ----
  f32x4 acc0 = {0.f, 0.f, 0.f, 0.f};
  f32x4 acc1 = {0.f, 0.f, 0.f, 0.f};
  const int db = wave & 3, kcg = wave >> 2;
#pragma unroll
  for (int jt = 0; jt < 8; jt++) {
    if (jt < ntiles) {
      const int j0 = jt * 256;
      const int buf = jt & 1;
      // write MY rows' p for this tile (bf16; zeros where masked)
#pragma unroll
      for (int tt = 0; tt < 4; tt++)
        if (j0 + 64 * tt <= rmax) {           // skip groups no chunk reads
          Ptile[buf][wave][64 * tt + lane] = bf16_bits(s0[jt * 4 + tt]);
          Ptile[buf][wave + 16][64 * tt + lane] = bf16_bits(s1[jt * 4 + tt]);
        }
      // Issue V loads BEFORE the barrier (independent of LDS; latency
      // overlaps the barrier drain). Guards match consumers.
      const size_t vrowbase = (size_t)(col0 + 16 * db + l15) * CL + j0;
      short8 vh_[2], vl_[2];
      bool vlive[2];
#pragma unroll
      for (int t2 = 0; t2 < 2; t2++) {
        const int kc = 2 * kcg + t2;
        vlive[t2] = (j0 + kc * 32 <= rmax);   // wave-uniform
        if (vlive[t2]) {
          const size_t vb = vrowbase + kc * 32 + quad * 8;
          vh_[t2] = *reinterpret_cast<const short8*>(vhT + vb);
          vl_[t2] = *reinterpret_cast<const short8*>(vlT + vb);
        }
      }
      __syncthreads();
#pragma unroll
      for (int t2 = 0; t2 < 2; t2++) {
        const int kc = 2 * kcg + t2;  // this wave's K-chunk of 32
        if (vlive[t2]) {
          const short8 pa0 =
              *reinterpret_cast<const short8*>(&Ptile[buf][l15][kc * 32 + quad * 8]);
          const short8 pa1 =
              *reinterpret_cast<const short8*>(&Ptile[buf][l15 + 16][kc * 32 + quad * 8]);
          acc0 = __builtin_amdgcn_mfma_f32_16x16x32_bf16(pa0, vl_[t2], acc0, 0, 0, 0);
          acc0 = __builtin_amdgcn_mfma_f32_16x16x32_bf16(pa0, vh_[t2], acc0, 0, 0, 0);
          acc1 = __builtin_amdgcn_mfma_f32_16x16x32_bf16(pa1, vl_[t2], acc1, 0, 0, 0);
          acc1 = __builtin_amdgcn_mfma_f32_16x16x32_bf16(pa1, vh_[t2], acc1, 0, 0, 0);
        }
      }
      // no trailing barrier: next P-write targets the other buffer
    }
  }

  // ---- Cross-wave K-group reduce + epilogue (32 rows) ----
#pragma unroll
  for (int r = 0; r < 4; r++) {
    Rtile[kcg][quad * 4 + r][db * 16 + l15] = acc0[r];
    Rtile[kcg][16 + quad * 4 + r][db * 16 + l15] = acc1[r];
  }
  __syncthreads();
  if (wave < 4) {  // wave u handles dim-block u for all 32 rows
#pragma unroll
    for (int r = 0; r < 8; r++) {
      const int row = quad * 8 + r;
      float o = (Rtile[0][row][wave * 16 + l15] + Rtile[1][row][wave * 16 + l15]) +
                (Rtile[2][row][wave * 16 + l15] + Rtile[3][row][wave * 16 + l15]);
      o *= invS[row];
      short sh, sl;
      split1(o, sh, sl);
      const size_t oidx = (size_t)(q0 + row) * CD + col0 + wave * 16 + l15;
      oh[oidx] = sh;
      ol[oidx] = sl;
    }
  }
}

extern "C" void kernel_launch(void* const* d_in, const int* in_sizes, int n_in,
                              void* d_out, int out_size, void* d_ws, size_t ws_size,
                              hipStream_t stream) {
  const float* x  = (const float*)d_in[0];
  const float* Wq = (const float*)d_in[1];
  const float* Wk = (const float*)d_in[2];
  const float* Wv = (const float*)d_in[3];
  const float* Wo = (const float*)d_in[4];
  float* out = (float*)d_out;

  // Workspace layout (56 MB total)
  char* ws = (char*)d_ws;
  short* xh  = (short*)(ws + (0ull  << 20));
  short* xl  = (short*)(ws + (4ull  << 20));
  short* wqh = (short*)(ws + (8ull  << 20));
  short* wql = (short*)(ws + (10ull << 20));
  short* wkh = (short*)(ws + (12ull << 20));
  short* wkl = (short*)(ws + (14ull << 20));
  short* wvh = (short*)(ws + (16ull << 20));
  short* wvl = (short*)(ws + (18ull << 20));
  short* woh = (short*)(ws + (20ull << 20));
  short* wol = (short*)(ws + (22ull << 20));
  short* qhp = (short*)(ws + (24ull << 20));
  short* qlp = (short*)(ws + (28ull << 20));
  short* khp = (short*)(ws + (32ull << 20));
  short* klp = (short*)(ws + (36ull << 20));
  short* vhT = (short*)(ws + (40ull << 20));
  short* vlT = (short*)(ws + (44ull << 20));
  short* ohp = (short*)(ws + (48ull << 20));
  short* olp = (short*)(ws + (52ull << 20));

  split_all<<<6144, 256, 0, stream>>>(x, Wq, Wk, Wv, Wo,
                                      xh, xl, wqh, wql, wkh, wkl,
                                      wvh, wvl, woh, wol);

  // Fused QKV: grid.x = 24, sel = x>>3 -> q/k planes row-major, vT transposed
  gemm128_split<<<dim3(24, CL / 128), 256, 0, stream>>>(
      xh, xl, wqh, wql, wkh, wkl, wvh, wvl,
      qhp, qlp, khp, klp, vhT, vlT, nullptr, 0);

  attn32<<<dim3(CL / 32, CH), 1024, 0, stream>>>(
      qhp, qlp, khp, klp, vhT, vlT, ohp, olp);

  // Wo: grid.x = 8 (sel = 0), fp32 out
  gemm128_split<<<dim3(8, CL / 128), 256, 0, stream>>>(
      ohp, olp, woh, wol, woh, wol, woh, wol,
      ohp, olp, ohp, olp, ohp, olp, out, 1);
}

// Round 15
// 410.101 us; speedup vs baseline: 1.1647x; 1.1647x over previous
//
#include <hip/hip_runtime.h>
#include <hip/hip_bf16.h>

// Problem constants (B=1)
#define CL 2048   // sequence length
#define CD 1024   // hidden
#define CH 16     // heads
#define CHD 64    // head dim
#define NEGS -1e30f

typedef __attribute__((ext_vector_type(8))) short short8;  // 8 x bf16 frag
typedef __attribute__((ext_vector_type(4))) float f32x4;
// One row of scores: 32 regs, static indices everywhere.
typedef __attribute__((ext_vector_type(32))) float f32x32;

// DPP wave reductions (R16; measured R9 ~-8us, kept: strictly better).
template <int CTRL>
__device__ __forceinline__ float dpp_add_step(float x) {
  int v = __builtin_amdgcn_update_dpp(0, __builtin_bit_cast(int, x),
                                      CTRL, 0xf, 0xf, true);
  return x + __builtin_bit_cast(float, v);
}
template <int CTRL>
__device__ __forceinline__ float dpp_max_step(float x) {
  int v = __builtin_amdgcn_update_dpp((int)0xff800000, __builtin_bit_cast(int, x),
                                      CTRL, 0xf, 0xf, false);
  return fmaxf(x, __builtin_bit_cast(float, v));
}
__device__ __forceinline__ float wave_sum(float x) {
  x = dpp_add_step<0x111>(x);  // row_shr:1
  x = dpp_add_step<0x112>(x);  // row_shr:2
  x = dpp_add_step<0x114>(x);  // row_shr:4
  x = dpp_add_step<0x118>(x);  // row_shr:8
  x = dpp_add_step<0x142>(x);  // row_bcast:15
  x = dpp_add_step<0x143>(x);  // row_bcast:31
  return __builtin_bit_cast(float,
      __builtin_amdgcn_readlane(__builtin_bit_cast(int, x), 63));
}
__device__ __forceinline__ float wave_max(float x) {
  x = dpp_max_step<0x111>(x);
  x = dpp_max_step<0x112>(x);
  x = dpp_max_step<0x114>(x);
  x = dpp_max_step<0x118>(x);
  x = dpp_max_step<0x142>(x);
  x = dpp_max_step<0x143>(x);
  return __builtin_bit_cast(float,
      __builtin_amdgcn_readlane(__builtin_bit_cast(int, x), 63));
}

__device__ __forceinline__ void split1(float v, short& h, short& l) {
  __hip_bfloat16 bh = __float2bfloat16(v);
  __hip_bfloat16 bl = __float2bfloat16(v - __bfloat162float(bh));
  h = __builtin_bit_cast(short, bh);
  l = __builtin_bit_cast(short, bl);
}
__device__ __forceinline__ unsigned short bf16_bits(float v) {
  __hip_bfloat16 b = __float2bfloat16(v);
  return (unsigned short)__builtin_bit_cast(short, b);
}

// ---- depth-5 tree helpers over f32x32 (one-shot; unguarded on purpose:
// relu MUST zero the causally-masked elems for the Ptile write) ----
__device__ __forceinline__ float tree_sum_valid(const f32x32& s) {
  float t[8];
#pragma unroll
  for (int i = 0; i < 8; i++) {
    const float a = s[i]      > -1e29f ? s[i]      : 0.f;
    const float b = s[i + 8]  > -1e29f ? s[i + 8]  : 0.f;
    const float c = s[i + 16] > -1e29f ? s[i + 16] : 0.f;
    const float d = s[i + 24] > -1e29f ? s[i + 24] : 0.f;
    t[i] = (a + b) + (c + d);
  }
#pragma unroll
  for (int i = 0; i < 4; i++) t[i] += t[i + 4];
  t[0] += t[2]; t[1] += t[3];
  return t[0] + t[1];
}
__device__ __forceinline__ float tree_max(const f32x32& s) {
  float t[8];
#pragma unroll
  for (int i = 0; i < 8; i++)
    t[i] = fmaxf(fmaxf(s[i], s[i + 8]), fmaxf(s[i + 16], s[i + 24]));
#pragma unroll
  for (int i = 0; i < 4; i++) t[i] = fmaxf(t[i], t[i + 4]);
  return fmaxf(fmaxf(t[0], t[2]), fmaxf(t[1], t[3]));
}
__device__ __forceinline__ float relu_store_sum(f32x32& s, float ts_) {
  float t[8];
#pragma unroll
  for (int i = 0; i < 8; i++) {
    float a = s[i] - ts_;      a = a > 0.f ? a : 0.f;
    float b = s[i + 8] - ts_;  b = b > 0.f ? b : 0.f;
    float c = s[i + 16] - ts_; c = c > 0.f ? c : 0.f;
    float d = s[i + 24] - ts_; d = d > 0.f ? d : 0.f;
    s[i] = a; s[i + 8] = b; s[i + 16] = c; s[i + 24] = d;
    t[i] = (a + b) + (c + d);
  }
#pragma unroll
  for (int i = 0; i < 4; i++) t[i] += t[i + 4];
  t[0] += t[2]; t[1] += t[3];
  return t[0] + t[1];
}

// R19/R20 fused 2-row Michelot (measured R12: attn 318->235us with the
// 32-row/2-per-wave structure). Ballot count on scalar pipe; it-invariant
// wave-uniform causal guards; per-row gated tau/cnt updates; freeze-stable.
__device__ __forceinline__ void entmax_pair(f32x32& s0, f32x32& s1,
                                            int g0, int g1,
                                            float& inv0, float& inv1) {
  const float ss0 = wave_sum(tree_sum_valid(s0));
  const float m0  = wave_max(tree_max(s0));
  const float ss1 = wave_sum(tree_sum_valid(s1));
  const float m1  = wave_max(tree_max(s1));
  float tau0 = m0 - 1.000001f, tau1 = m1 - 1.000001f;
  int cnt0 = 0, cnt1 = 0;
  for (int it = 0; it < 64; it++) {
    float sum0 = 0.f, sum1 = 0.f;
    int c0 = 0, c1 = 0;
#pragma unroll
    for (int jt = 0; jt < 8; jt++) {
      if (jt * 256 <= g0) {             // wave-uniform causal guard (row 0)
#pragma unroll
        for (int tt = 0; tt < 4; tt++) {
          const float a = s0[jt * 4 + tt];
          const bool pr = a > tau0;
          sum0 += pr ? a : 0.f;
          c0 += (int)__popcll(__ballot(pr));
        }
      }
      if (jt * 256 <= g1) {             // wave-uniform causal guard (row 1)
#pragma unroll
        for (int tt = 0; tt < 4; tt++) {
          const float a = s1[jt * 4 + tt];
          const bool pr = a > tau1;
          sum1 += pr ? a : 0.f;
          c1 += (int)__popcll(__ballot(pr));
        }
      }
    }
    const float cs0 = wave_sum(sum0);   // two independent DPP chains (ILP)
    const float cs1 = wave_sum(sum1);
    const bool st0 = (c0 == cnt0), st1 = (c1 == cnt1);
    if (st0 && st1) break;
    if (!st0) { cnt0 = c0; tau0 = (cs0 - 1.f) / (float)c0; }
    if (!st1) { cnt1 = c1; tau1 = (cs1 - 1.f) / (float)c1; }
  }
  const float ts0 = (ss0 - 1.f) / (float)cnt0;
  const float ts1 = (ss1 - 1.f) / (float)cnt1;
  inv0 = 1.f / (wave_sum(relu_store_sum(s0, ts0)) + 1e-10f);
  inv1 = 1.f / (wave_sum(relu_store_sum(s1, ts1)) + 1e-10f);
}

// One fused split kernel: fp32 -> bf16 hi/lo planes for x and 4 weights.
__global__ __launch_bounds__(256) void split_all(
    const float* __restrict__ x,  const float* __restrict__ wq,
    const float* __restrict__ wk, const float* __restrict__ wv,
    const float* __restrict__ wo,
    short* __restrict__ xh,  short* __restrict__ xl,
    short* __restrict__ wqh, short* __restrict__ wql,
    short* __restrict__ wkh, short* __restrict__ wkl,
    short* __restrict__ wvh, short* __restrict__ wvl,
    short* __restrict__ woh, short* __restrict__ wol) {
  const int b = blockIdx.x;
  const float* src; short *dh, *dl; int i0;
  if      (b < 2048) { src = x;  dh = xh;  dl = xl;  i0 = b; }
  else if (b < 3072) { src = wq; dh = wqh; dl = wql; i0 = b - 2048; }
  else if (b < 4096) { src = wk; dh = wkh; dl = wkl; i0 = b - 3072; }
  else if (b < 5120) { src = wv; dh = wvh; dl = wvl; i0 = b - 4096; }
  else               { src = wo; dh = woh; dl = wol; i0 = b - 5120; }
  const int i = i0 * 256 + threadIdx.x;
  const float4 v = reinterpret_cast<const float4*>(src)[i];
  const float vv[4] = {v.x, v.y, v.z, v.w};
  short hh[4], ll[4];
#pragma unroll
  for (int e = 0; e < 4; e++) split1(vv[e], hh[e], ll[e]);
  reinterpret_cast<short4*>(dh)[i] = make_short4(hh[0], hh[1], hh[2], hh[3]);
  reinterpret_cast<short4*>(dl)[i] = make_short4(ll[0], ll[1], ll[2], ll[3]);
}

// C[2048,1024] = (Ah+Al) * (B?h+B?l)^T via 3-term split-bf16 MFMA.
// 128x128 tile/WG. R21 (measured win, ~-58us vs BK=32): BK=64 — two 32-K
// sub-steps per barrier pair. LDS 64KB (2 blocks/CU). Numerics bit-identical.
// Lane-linear staging: LDS off = i*1024 + lane*16; global row = i*8+(lane>>3),
// chunk = (lane&7)*8.
__global__ __launch_bounds__(256, 2) void gemm128_split(
    const short* __restrict__ Ah, const short* __restrict__ Al,
    const short* __restrict__ B0h, const short* __restrict__ B0l,
    const short* __restrict__ B1h, const short* __restrict__ B1l,
    const short* __restrict__ B2h, const short* __restrict__ B2l,
    short* __restrict__ O0h, short* __restrict__ O0l,
    short* __restrict__ O1h, short* __restrict__ O1l,
    short* __restrict__ O2h, short* __restrict__ O2l,
    float* __restrict__ Cf, int fp32out) {
  __shared__ short AhS[128][64], AlS[128][64], BhS[128][64], BlS[128][64];
  const int tid = threadIdx.x, lane = tid & 63, wave = tid >> 6;
  const int l15 = lane & 15, quad = lane >> 4;
  const int sel = blockIdx.x >> 3, nb = blockIdx.x & 7;
  const short* Bh = sel == 0 ? B0h : (sel == 1 ? B1h : B2h);
  const short* Bl = sel == 0 ? B0l : (sel == 1 ? B1l : B2l);
  const int m0 = blockIdx.y * 128, n0 = nb * 128;
  const int wm = (wave >> 1) * 64, wn = (wave & 1) * 64;

  f32x4 acc[4][4];
#pragma unroll
  for (int i = 0; i < 4; i++)
#pragma unroll
    for (int j = 0; j < 4; j++) acc[i][j] = {0.f, 0.f, 0.f, 0.f};

  const short* gsrc = wave == 0 ? Ah : wave == 1 ? Al : wave == 2 ? Bh : Bl;
  short(*ldst)[64] = wave == 0 ? AhS : wave == 1 ? AlS : wave == 2 ? BhS : BlS;
  const int srow0 = (wave < 2) ? m0 : n0;
  const int sr = lane >> 3, skc = (lane & 7) * 8;  // row-in-8, 16B chunk

  for (int k0 = 0; k0 < CD; k0 += 64) {
    // 16 x global_load_lds_dwordx4: wave-uniform LDS base + lane*16.
#pragma unroll
    for (int i = 0; i < 16; i++) {
      const short* gp =
          gsrc + (size_t)(srow0 + i * 8 + sr) * CD + k0 + skc;
      __builtin_amdgcn_global_load_lds(
          (const __attribute__((address_space(1))) void*)gp,
          (__attribute__((address_space(3))) void*)((char*)&ldst[0][0] + i * 1024),
          16, 0, 0);
    }
    __syncthreads();
#pragma unroll
    for (int kb = 0; kb < 2; kb++) {
      short8 a_h[4], a_l[4], b_h[4], b_l[4];
#pragma unroll
      for (int i = 0; i < 4; i++) {
        a_h[i] = *reinterpret_cast<const short8*>(&AhS[wm + i * 16 + l15][kb * 32 + quad * 8]);
        a_l[i] = *reinterpret_cast<const short8*>(&AlS[wm + i * 16 + l15][kb * 32 + quad * 8]);
        b_h[i] = *reinterpret_cast<const short8*>(&BhS[wn + i * 16 + l15][kb * 32 + quad * 8]);
        b_l[i] = *reinterpret_cast<const short8*>(&BlS[wn + i * 16 + l15][kb * 32 + quad * 8]);
      }
#pragma unroll
      for (int im = 0; im < 4; im++)
#pragma unroll
        for (int in = 0; in < 4; in++) {
          acc[im][in] = __builtin_amdgcn_mfma_f32_16x16x32_bf16(a_h[im], b_l[in], acc[im][in], 0, 0, 0);
          acc[im][in] = __builtin_amdgcn_mfma_f32_16x16x32_bf16(a_l[im], b_h[in], acc[im][in], 0, 0, 0);
          acc[im][in] = __builtin_amdgcn_mfma_f32_16x16x32_bf16(a_h[im], b_h[in], acc[im][in], 0, 0, 0);
        }
    }
    __syncthreads();
  }

#pragma unroll
  for (int im = 0; im < 4; im++)
#pragma unroll
    for (int in = 0; in < 4; in++)
#pragma unroll
      for (int r = 0; r < 4; r++) {
        const int mr = m0 + wm + im * 16 + quad * 4 + r;
        const int nc = n0 + wn + in * 16 + l15;
        const float val = acc[im][in][r];
        if (fp32out) {
          Cf[(size_t)mr * CD + nc] = val;
        } else {
          short sh, sl;
          split1(val, sh, sl);
          if (sel == 0) {
            O0h[(size_t)mr * CD + nc] = sh; O0l[(size_t)mr * CD + nc] = sl;
          } else if (sel == 1) {
            O1h[(size_t)mr * CD + nc] = sh; O1l[(size_t)mr * CD + nc] = sl;
          } else {  // vT[dim][seq]
            O2h[(size_t)nc * CL + mr] = sh; O2l[(size_t)nc * CL + mr] = sl;
          }
        }
      }
}

// R23: attn32 reverted EXACTLY to the R12-measured 235us form (merged single
// dispatch, loads at consumers, no prefetch). R22's register prefetch spilled
// the score vectors to scratch (WRITE_SIZE 8->141MB, attn 235->308us):
// conditionally-initialized register arrays living across a barrier invite
// spills — reverted wholesale. 32 q-rows per WG (2 rows per wave), grid
// (64,16), LDS 132KB, fused 2-row Michelot.
__global__ __launch_bounds__(1024, 4) void attn32(
    const short* __restrict__ qh, const short* __restrict__ ql,
    const short* __restrict__ kh, const short* __restrict__ kl,
    const short* __restrict__ vhT, const short* __restrict__ vlT,
    short* __restrict__ oh, short* __restrict__ ol) {
  __shared__ float Stile[2][32][260];           // 66.6 KB
  __shared__ unsigned short Ptile[2][32][264];  // 33.8 KB
  __shared__ float Rtile[4][32][68];            // 34.8 KB partial PV
  __shared__ float invS[32];                    // total ~132 KB

  const int tid = threadIdx.x, lane = tid & 63, wave = tid >> 6;
  const int l15 = lane & 15, quad = lane >> 4;
  const int bx = blockIdx.x;
  const int qb = (bx & 1) ? (63 - (bx >> 1)) : (bx >> 1);  // heavy+light mix
  const int h = blockIdx.y, q0 = qb * 32, col0 = h * CHD;
  const int g0 = q0 + wave;                   // wave's row in group A (0..15)
  const int g1 = q0 + 16 + wave;              // wave's row in group B (16..31)
  const int ntiles = (q0 + 287) >> 8;         // 256-col tiles covering 0..q0+31
  const int rmax = q0 + 31;                   // last valid column in this block

  // A-frags for both row groups: m=l15, k=kb*32+quad*8+j [m89/m91 layout]
  short8 a0h[2], a0l[2], a1h[2], a1l[2];
  {
    const size_t qbA = (size_t)(q0 + l15) * CD + col0 + quad * 8;
    const size_t qbB = (size_t)(q0 + 16 + l15) * CD + col0 + quad * 8;
#pragma unroll
    for (int kb = 0; kb < 2; kb++) {
      a0h[kb] = *reinterpret_cast<const short8*>(qh + qbA + kb * 32);
      a0l[kb] = *reinterpret_cast<const short8*>(ql + qbA + kb * 32);
      a1h[kb] = *reinterpret_cast<const short8*>(qh + qbB + kb * 32);
      a1l[kb] = *reinterpret_cast<const short8*>(ql + qbB + kb * 32);
    }
  }

  f32x32 s0, s1;
#pragma unroll
  for (int t = 0; t < 32; t++) { s0[t] = NEGS; s1[t] = NEGS; }

  // ---- Phase 1: scores (both row groups share the wave's K B-frag) ----
#pragma unroll
  for (int jt = 0; jt < 8; jt++) {
    if (jt < ntiles) {                        // WG-uniform
      const int j0 = jt * 256;
      const int buf = jt & 1;
      if (j0 + 16 * wave <= rmax) {           // wave-uniform causal-tail skip
        const size_t kbase = (size_t)(j0 + 16 * wave + l15) * CD + col0 + quad * 8;
        f32x4 c0 = {0.f, 0.f, 0.f, 0.f};
        f32x4 c1 = {0.f, 0.f, 0.f, 0.f};
#pragma unroll
        for (int kb = 0; kb < 2; kb++) {
          const short8 b_h = *reinterpret_cast<const short8*>(kh + kbase + kb * 32);
          const short8 b_l = *reinterpret_cast<const short8*>(kl + kbase + kb * 32);
          c0 = __builtin_amdgcn_mfma_f32_16x16x32_bf16(a0l[kb], b_l, c0, 0, 0, 0);
          c0 = __builtin_amdgcn_mfma_f32_16x16x32_bf16(a0h[kb], b_l, c0, 0, 0, 0);
          c0 = __builtin_amdgcn_mfma_f32_16x16x32_bf16(a0l[kb], b_h, c0, 0, 0, 0);
          c0 = __builtin_amdgcn_mfma_f32_16x16x32_bf16(a0h[kb], b_h, c0, 0, 0, 0);
          c1 = __builtin_amdgcn_mfma_f32_16x16x32_bf16(a1l[kb], b_l, c1, 0, 0, 0);
          c1 = __builtin_amdgcn_mfma_f32_16x16x32_bf16(a1h[kb], b_l, c1, 0, 0, 0);
          c1 = __builtin_amdgcn_mfma_f32_16x16x32_bf16(a1l[kb], b_h, c1, 0, 0, 0);
          c1 = __builtin_amdgcn_mfma_f32_16x16x32_bf16(a1h[kb], b_h, c1, 0, 0, 0);
        }
        // C layout: col(seq) = 16*wave + l15, row(q) = quad*4 + r (+16 for B)
#pragma unroll
        for (int r = 0; r < 4; r++) {
          Stile[buf][quad * 4 + r][16 * wave + l15] = c0[r];
          Stile[buf][16 + quad * 4 + r][16 * wave + l15] = c1[r];
        }
      }
      __syncthreads();
      // Gather MY rows: lane ll owns cols j0 + 64*tt + ll (2-way = free)
#pragma unroll
      for (int tt = 0; tt < 4; tt++) {
        const int col = j0 + 64 * tt + lane;
        if (j0 + 64 * tt <= g0) {             // wave-uniform group-valid check
          const float v = Stile[buf][wave][64 * tt + lane] * 0.125f;  // exact
          s0[jt * 4 + tt] = (col <= g0) ? v : NEGS;
        }
        if (j0 + 64 * tt <= g1) {
          const float v = Stile[buf][wave + 16][64 * tt + lane] * 0.125f;
          s1[jt * 4 + tt] = (col <= g1) ? v : NEGS;
        }
      }
      // no trailing barrier: next scatter targets the other buffer
    }
  }

  // ---- Phase 2: fused 2-row Michelot per wave (32 rows in parallel) ----
  float inv0, inv1;
  entmax_pair(s0, s1, g0, g1, inv0, inv1);
  if (lane == 0) { invS[wave] = inv0; invS[wave + 16] = inv1; }

  // ---- Phase 3: P @ V (wave = (kgroup, dim-block); both row groups) ----
  f32x4 acc0 = {0.f, 0.f, 0.f, 0.f};
  f32x4 acc1 = {0.f, 0.f, 0.f, 0.f};
  const int db = wave & 3, kcg = wave >> 2;
#pragma unroll
  for (int jt = 0; jt < 8; jt++) {
    if (jt < ntiles) {
      const int j0 = jt * 256;
      const int buf = jt & 1;
      // write MY rows' p for this tile (bf16; zeros where masked)
#pragma unroll
      for (int tt = 0; tt < 4; tt++)
        if (j0 + 64 * tt <= rmax) {           // skip groups no chunk reads
          Ptile[buf][wave][64 * tt + lane] = bf16_bits(s0[jt * 4 + tt]);
          Ptile[buf][wave + 16][64 * tt + lane] = bf16_bits(s1[jt * 4 + tt]);
        }
      __syncthreads();
      const size_t vrowbase =
          (size_t)(col0 + 16 * db + l15) * CL + j0;
#pragma unroll
      for (int t2 = 0; t2 < 2; t2++) {
        const int kc = 2 * kcg + t2;  // this wave's K-chunk of 32
        if (j0 + kc * 32 <= rmax) {           // wave-uniform causal-tail skip
          const short8 pa0 =
              *reinterpret_cast<const short8*>(&Ptile[buf][l15][kc * 32 + quad * 8]);
          const short8 pa1 =
              *reinterpret_cast<const short8*>(&Ptile[buf][l15 + 16][kc * 32 + quad * 8]);
          const size_t vb = vrowbase + kc * 32 + quad * 8;
          const short8 vbh = *reinterpret_cast<const short8*>(vhT + vb);
          const short8 vbl = *reinterpret_cast<const short8*>(vlT + vb);
          acc0 = __builtin_amdgcn_mfma_f32_16x16x32_bf16(pa0, vbl, acc0, 0, 0, 0);
          acc0 = __builtin_amdgcn_mfma_f32_16x16x32_bf16(pa0, vbh, acc0, 0, 0, 0);
          acc1 = __builtin_amdgcn_mfma_f32_16x16x32_bf16(pa1, vbl, acc1, 0, 0, 0);
          acc1 = __builtin_amdgcn_mfma_f32_16x16x32_bf16(pa1, vbh, acc1, 0, 0, 0);
        }
      }
      // no trailing barrier: next P-write targets the other buffer
    }
  }

  // ---- Cross-wave K-group reduce + epilogue (32 rows) ----
#pragma unroll
  for (int r = 0; r < 4; r++) {
    Rtile[kcg][quad * 4 + r][db * 16 + l15] = acc0[r];
    Rtile[kcg][16 + quad * 4 + r][db * 16 + l15] = acc1[r];
  }
  __syncthreads();
  if (wave < 4) {  // wave u handles dim-block u for all 32 rows
#pragma unroll
    for (int r = 0; r < 8; r++) {
      const int row = quad * 8 + r;
      float o = (Rtile[0][row][wave * 16 + l15] + Rtile[1][row][wave * 16 + l15]) +
                (Rtile[2][row][wave * 16 + l15] + Rtile[3][row][wave * 16 + l15]);
      o *= invS[row];
      short sh, sl;
      split1(o, sh, sl);
      const size_t oidx = (size_t)(q0 + row) * CD + col0 + wave * 16 + l15;
      oh[oidx] = sh;
      ol[oidx] = sl;
    }
  }
}

extern "C" void kernel_launch(void* const* d_in, const int* in_sizes, int n_in,
                              void* d_out, int out_size, void* d_ws, size_t ws_size,
                              hipStream_t stream) {
  const float* x  = (const float*)d_in[0];
  const float* Wq = (const float*)d_in[1];
  const float* Wk = (const float*)d_in[2];
  const float* Wv = (const float*)d_in[3];
  const float* Wo = (const float*)d_in[4];
  float* out = (float*)d_out;

  // Workspace layout (56 MB total)
  char* ws = (char*)d_ws;
  short* xh  = (short*)(ws + (0ull  << 20));
  short* xl  = (short*)(ws + (4ull  << 20));
  short* wqh = (short*)(ws + (8ull  << 20));
  short* wql = (short*)(ws + (10ull << 20));
  short* wkh = (short*)(ws + (12ull << 20));
  short* wkl = (short*)(ws + (14ull << 20));
  short* wvh = (short*)(ws + (16ull << 20));
  short* wvl = (short*)(ws + (18ull << 20));
  short* woh = (short*)(ws + (20ull << 20));
  short* wol = (short*)(ws + (22ull << 20));
  short* qhp = (short*)(ws + (24ull << 20));
  short* qlp = (short*)(ws + (28ull << 20));
  short* khp = (short*)(ws + (32ull << 20));
  short* klp = (short*)(ws + (36ull << 20));
  short* vhT = (short*)(ws + (40ull << 20));
  short* vlT = (short*)(ws + (44ull << 20));
  short* ohp = (short*)(ws + (48ull << 20));
  short* olp = (short*)(ws + (52ull << 20));

  split_all<<<6144, 256, 0, stream>>>(x, Wq, Wk, Wv, Wo,
                                      xh, xl, wqh, wql, wkh, wkl,
                                      wvh, wvl, woh, wol);

  // Fused QKV: grid.x = 24, sel = x>>3 -> q/k planes row-major, vT transposed
  gemm128_split<<<dim3(24, CL / 128), 256, 0, stream>>>(
      xh, xl, wqh, wql, wkh, wkl, wvh, wvl,
      qhp, qlp, khp, klp, vhT, vlT, nullptr, 0);

  attn32<<<dim3(CL / 32, CH), 1024, 0, stream>>>(
      qhp, qlp, khp, klp, vhT, vlT, ohp, olp);

  // Wo: grid.x = 8 (sel = 0), fp32 out
  gemm128_split<<<dim3(8, CL / 128), 256, 0, stream>>>(
      ohp, olp, woh, wol, woh, wol, woh, wol,
      ohp, olp, ohp, olp, ohp, olp, out, 1);
}

// Round 16
// 407.402 us; speedup vs baseline: 1.1724x; 1.0066x over previous
//
#include <hip/hip_runtime.h>
#include <hip/hip_bf16.h>

// Problem constants (B=1)
#define CL 2048   // sequence length
#define CD 1024   // hidden
#define CH 16     // heads
#define CHD 64    // head dim
#define NEGS -1e30f

typedef __attribute__((ext_vector_type(8))) short short8;  // 8 x bf16 frag
typedef __attribute__((ext_vector_type(4))) float f32x4;
// One row of scores: 32 regs, static indices everywhere.
typedef __attribute__((ext_vector_type(32))) float f32x32;

// DPP wave reductions (R16; measured R9 ~-8us, kept: strictly better).
template <int CTRL>
__device__ __forceinline__ float dpp_add_step(float x) {
  int v = __builtin_amdgcn_update_dpp(0, __builtin_bit_cast(int, x),
                                      CTRL, 0xf, 0xf, true);
  return x + __builtin_bit_cast(float, v);
}
template <int CTRL>
__device__ __forceinline__ float dpp_max_step(float x) {
  int v = __builtin_amdgcn_update_dpp((int)0xff800000, __builtin_bit_cast(int, x),
                                      CTRL, 0xf, 0xf, false);
  return fmaxf(x, __builtin_bit_cast(float, v));
}
__device__ __forceinline__ float wave_sum(float x) {
  x = dpp_add_step<0x111>(x);  // row_shr:1
  x = dpp_add_step<0x112>(x);  // row_shr:2
  x = dpp_add_step<0x114>(x);  // row_shr:4
  x = dpp_add_step<0x118>(x);  // row_shr:8
  x = dpp_add_step<0x142>(x);  // row_bcast:15
  x = dpp_add_step<0x143>(x);  // row_bcast:31
  return __builtin_bit_cast(float,
      __builtin_amdgcn_readlane(__builtin_bit_cast(int, x), 63));
}
__device__ __forceinline__ float wave_max(float x) {
  x = dpp_max_step<0x111>(x);
  x = dpp_max_step<0x112>(x);
  x = dpp_max_step<0x114>(x);
  x = dpp_max_step<0x118>(x);
  x = dpp_max_step<0x142>(x);
  x = dpp_max_step<0x143>(x);
  return __builtin_bit_cast(float,
      __builtin_amdgcn_readlane(__builtin_bit_cast(int, x), 63));
}

__device__ __forceinline__ void split1(float v, short& h, short& l) {
  __hip_bfloat16 bh = __float2bfloat16(v);
  __hip_bfloat16 bl = __float2bfloat16(v - __bfloat162float(bh));
  h = __builtin_bit_cast(short, bh);
  l = __builtin_bit_cast(short, bl);
}
__device__ __forceinline__ unsigned short bf16_bits(float v) {
  __hip_bfloat16 b = __float2bfloat16(v);
  return (unsigned short)__builtin_bit_cast(short, b);
}

// ---- depth-5 tree helpers over f32x32 (one-shot; unguarded on purpose:
// relu MUST zero the causally-masked elems for the Ptile write) ----
__device__ __forceinline__ float tree_sum_valid(const f32x32& s) {
  float t[8];
#pragma unroll
  for (int i = 0; i < 8; i++) {
    const float a = s[i]      > -1e29f ? s[i]      : 0.f;
    const float b = s[i + 8]  > -1e29f ? s[i + 8]  : 0.f;
    const float c = s[i + 16] > -1e29f ? s[i + 16] : 0.f;
    const float d = s[i + 24] > -1e29f ? s[i + 24] : 0.f;
    t[i] = (a + b) + (c + d);
  }
#pragma unroll
  for (int i = 0; i < 4; i++) t[i] += t[i + 4];
  t[0] += t[2]; t[1] += t[3];
  return t[0] + t[1];
}
__device__ __forceinline__ float tree_max(const f32x32& s) {
  float t[8];
#pragma unroll
  for (int i = 0; i < 8; i++)
    t[i] = fmaxf(fmaxf(s[i], s[i + 8]), fmaxf(s[i + 16], s[i + 24]));
#pragma unroll
  for (int i = 0; i < 4; i++) t[i] = fmaxf(t[i], t[i + 4]);
  return fmaxf(fmaxf(t[0], t[2]), fmaxf(t[1], t[3]));
}
__device__ __forceinline__ float relu_store_sum(f32x32& s, float ts_) {
  float t[8];
#pragma unroll
  for (int i = 0; i < 8; i++) {
    float a = s[i] - ts_;      a = a > 0.f ? a : 0.f;
    float b = s[i + 8] - ts_;  b = b > 0.f ? b : 0.f;
    float c = s[i + 16] - ts_; c = c > 0.f ? c : 0.f;
    float d = s[i + 24] - ts_; d = d > 0.f ? d : 0.f;
    s[i] = a; s[i + 8] = b; s[i + 16] = c; s[i + 24] = d;
    t[i] = (a + b) + (c + d);
  }
#pragma unroll
  for (int i = 0; i < 4; i++) t[i] += t[i + 4];
  t[0] += t[2]; t[1] += t[3];
  return t[0] + t[1];
}

// R19/R20 fused 2-row Michelot (measured R12: attn 318->235us with the
// 32-row/2-per-wave structure). Ballot count on scalar pipe; it-invariant
// wave-uniform causal guards; per-row gated tau/cnt updates; freeze-stable.
__device__ __forceinline__ void entmax_pair(f32x32& s0, f32x32& s1,
                                            int g0, int g1,
                                            float& inv0, float& inv1) {
  const float ss0 = wave_sum(tree_sum_valid(s0));
  const float m0  = wave_max(tree_max(s0));
  const float ss1 = wave_sum(tree_sum_valid(s1));
  const float m1  = wave_max(tree_max(s1));
  float tau0 = m0 - 1.000001f, tau1 = m1 - 1.000001f;
  int cnt0 = 0, cnt1 = 0;
  for (int it = 0; it < 64; it++) {
    float sum0 = 0.f, sum1 = 0.f;
    int c0 = 0, c1 = 0;
#pragma unroll
    for (int jt = 0; jt < 8; jt++) {
      if (jt * 256 <= g0) {             // wave-uniform causal guard (row 0)
#pragma unroll
        for (int tt = 0; tt < 4; tt++) {
          const float a = s0[jt * 4 + tt];
          const bool pr = a > tau0;
          sum0 += pr ? a : 0.f;
          c0 += (int)__popcll(__ballot(pr));
        }
      }
      if (jt * 256 <= g1) {             // wave-uniform causal guard (row 1)
#pragma unroll
        for (int tt = 0; tt < 4; tt++) {
          const float a = s1[jt * 4 + tt];
          const bool pr = a > tau1;
          sum1 += pr ? a : 0.f;
          c1 += (int)__popcll(__ballot(pr));
        }
      }
    }
    const float cs0 = wave_sum(sum0);   // two independent DPP chains (ILP)
    const float cs1 = wave_sum(sum1);
    const bool st0 = (c0 == cnt0), st1 = (c1 == cnt1);
    if (st0 && st1) break;
    if (!st0) { cnt0 = c0; tau0 = (cs0 - 1.f) / (float)c0; }
    if (!st1) { cnt1 = c1; tau1 = (cs1 - 1.f) / (float)c1; }
  }
  const float ts0 = (ss0 - 1.f) / (float)cnt0;
  const float ts1 = (ss1 - 1.f) / (float)cnt1;
  inv0 = 1.f / (wave_sum(relu_store_sum(s0, ts0)) + 1e-10f);
  inv1 = 1.f / (wave_sum(relu_store_sum(s1, ts1)) + 1e-10f);
}

// One fused split kernel: fp32 -> bf16 hi/lo planes for x and 4 weights.
__global__ __launch_bounds__(256) void split_all(
    const float* __restrict__ x,  const float* __restrict__ wq,
    const float* __restrict__ wk, const float* __restrict__ wv,
    const float* __restrict__ wo,
    short* __restrict__ xh,  short* __restrict__ xl,
    short* __restrict__ wqh, short* __restrict__ wql,
    short* __restrict__ wkh, short* __restrict__ wkl,
    short* __restrict__ wvh, short* __restrict__ wvl,
    short* __restrict__ woh, short* __restrict__ wol) {
  const int b = blockIdx.x;
  const float* src; short *dh, *dl; int i0;
  if      (b < 2048) { src = x;  dh = xh;  dl = xl;  i0 = b; }
  else if (b < 3072) { src = wq; dh = wqh; dl = wql; i0 = b - 2048; }
  else if (b < 4096) { src = wk; dh = wkh; dl = wkl; i0 = b - 3072; }
  else if (b < 5120) { src = wv; dh = wvh; dl = wvl; i0 = b - 4096; }
  else               { src = wo; dh = woh; dl = wol; i0 = b - 5120; }
  const int i = i0 * 256 + threadIdx.x;
  const float4 v = reinterpret_cast<const float4*>(src)[i];
  const float vv[4] = {v.x, v.y, v.z, v.w};
  short hh[4], ll[4];
#pragma unroll
  for (int e = 0; e < 4; e++) split1(vv[e], hh[e], ll[e]);
  reinterpret_cast<short4*>(dh)[i] = make_short4(hh[0], hh[1], hh[2], hh[3]);
  reinterpret_cast<short4*>(dl)[i] = make_short4(ll[0], ll[1], ll[2], ll[3]);
}

// C[2048,1024] = (Ah+Al) * (B?h+B?l)^T via 3-term split-bf16 MFMA.
// 128x128 tile/WG. R21 (measured win, ~-58us vs BK=32): BK=64 — two 32-K
// sub-steps per barrier pair. LDS 64KB (2 blocks/CU). Numerics bit-identical.
// Lane-linear staging: LDS off = i*1024 + lane*16; global row = i*8+(lane>>3),
// chunk = (lane&7)*8.
__global__ __launch_bounds__(256, 2) void gemm128_split(
    const short* __restrict__ Ah, const short* __restrict__ Al,
    const short* __restrict__ B0h, const short* __restrict__ B0l,
    const short* __restrict__ B1h, const short* __restrict__ B1l,
    const short* __restrict__ B2h, const short* __restrict__ B2l,
    short* __restrict__ O0h, short* __restrict__ O0l,
    short* __restrict__ O1h, short* __restrict__ O1l,
    short* __restrict__ O2h, short* __restrict__ O2l,
    float* __restrict__ Cf, int fp32out) {
  __shared__ short AhS[128][64], AlS[128][64], BhS[128][64], BlS[128][64];
  const int tid = threadIdx.x, lane = tid & 63, wave = tid >> 6;
  const int l15 = lane & 15, quad = lane >> 4;
  const int sel = blockIdx.x >> 3, nb = blockIdx.x & 7;
  const short* Bh = sel == 0 ? B0h : (sel == 1 ? B1h : B2h);
  const short* Bl = sel == 0 ? B0l : (sel == 1 ? B1l : B2l);
  const int m0 = blockIdx.y * 128, n0 = nb * 128;
  const int wm = (wave >> 1) * 64, wn = (wave & 1) * 64;

  f32x4 acc[4][4];
#pragma unroll
  for (int i = 0; i < 4; i++)
#pragma unroll
    for (int j = 0; j < 4; j++) acc[i][j] = {0.f, 0.f, 0.f, 0.f};

  const short* gsrc = wave == 0 ? Ah : wave == 1 ? Al : wave == 2 ? Bh : Bl;
  short(*ldst)[64] = wave == 0 ? AhS : wave == 1 ? AlS : wave == 2 ? BhS : BlS;
  const int srow0 = (wave < 2) ? m0 : n0;
  const int sr = lane >> 3, skc = (lane & 7) * 8;  // row-in-8, 16B chunk

  for (int k0 = 0; k0 < CD; k0 += 64) {
    // 16 x global_load_lds_dwordx4: wave-uniform LDS base + lane*16.
#pragma unroll
    for (int i = 0; i < 16; i++) {
      const short* gp =
          gsrc + (size_t)(srow0 + i * 8 + sr) * CD + k0 + skc;
      __builtin_amdgcn_global_load_lds(
          (const __attribute__((address_space(1))) void*)gp,
          (__attribute__((address_space(3))) void*)((char*)&ldst[0][0] + i * 1024),
          16, 0, 0);
    }
    __syncthreads();
#pragma unroll
    for (int kb = 0; kb < 2; kb++) {
      short8 a_h[4], a_l[4], b_h[4], b_l[4];
#pragma unroll
      for (int i = 0; i < 4; i++) {
        a_h[i] = *reinterpret_cast<const short8*>(&AhS[wm + i * 16 + l15][kb * 32 + quad * 8]);
        a_l[i] = *reinterpret_cast<const short8*>(&AlS[wm + i * 16 + l15][kb * 32 + quad * 8]);
        b_h[i] = *reinterpret_cast<const short8*>(&BhS[wn + i * 16 + l15][kb * 32 + quad * 8]);
        b_l[i] = *reinterpret_cast<const short8*>(&BlS[wn + i * 16 + l15][kb * 32 + quad * 8]);
      }
#pragma unroll
      for (int im = 0; im < 4; im++)
#pragma unroll
        for (int in = 0; in < 4; in++) {
          acc[im][in] = __builtin_amdgcn_mfma_f32_16x16x32_bf16(a_h[im], b_l[in], acc[im][in], 0, 0, 0);
          acc[im][in] = __builtin_amdgcn_mfma_f32_16x16x32_bf16(a_l[im], b_h[in], acc[im][in], 0, 0, 0);
          acc[im][in] = __builtin_amdgcn_mfma_f32_16x16x32_bf16(a_h[im], b_h[in], acc[im][in], 0, 0, 0);
        }
    }
    __syncthreads();
  }

#pragma unroll
  for (int im = 0; im < 4; im++)
#pragma unroll
    for (int in = 0; in < 4; in++)
#pragma unroll
      for (int r = 0; r < 4; r++) {
        const int mr = m0 + wm + im * 16 + quad * 4 + r;
        const int nc = n0 + wn + in * 16 + l15;
        const float val = acc[im][in][r];
        if (fp32out) {
          Cf[(size_t)mr * CD + nc] = val;
        } else {
          short sh, sl;
          split1(val, sh, sl);
          if (sel == 0) {
            O0h[(size_t)mr * CD + nc] = sh; O0l[(size_t)mr * CD + nc] = sl;
          } else if (sel == 1) {
            O1h[(size_t)mr * CD + nc] = sh; O1l[(size_t)mr * CD + nc] = sl;
          } else {  // vT[dim][seq]
            O2h[(size_t)nc * CL + mr] = sh; O2l[(size_t)nc * CL + mr] = sl;
          }
        }
      }
}

// R24: attn32 = R12/R15-measured 235.8us kernel + LDS OVERLAY -> 2 blocks/CU.
// R13's split decomposition: per-round cost = F(~44us fixed: Michelot chain +
// prologue/epilogue) + 3.7us/tile; 4 rounds * F ~ 178us of 235 => fixed cost
// dominates and nothing co-resident hides it (1 block/CU at 132KB LDS).
// Overlay: Stile (phase 1 only) shares storage with Ptile+Rtile (phase 3
// only): max(66560, 33792+34816) = 68608 B + invS ~ 67.2KB => TWO blocks/CU
// (137KB < 160; VGPR 64 allows 32 waves/CU). One block's Michelot overlaps
// the other's MFMA/memory phases. Correctness: single WG-uniform barrier
// between phase 2 and phase 3 (first Ptile write aliases Stile; every wave's
// last Stile read precedes it). Ptile/Rtile mutually disjoint. All b128 LDS
// reads stay 16B-aligned (row strides 1040/528/272 B; base align 16).
__global__ __launch_bounds__(1024, 4) void attn32(
    const short* __restrict__ qh, const short* __restrict__ ql,
    const short* __restrict__ kh, const short* __restrict__ kl,
    const short* __restrict__ vhT, const short* __restrict__ vlT,
    short* __restrict__ oh, short* __restrict__ ol) {
  __shared__ __align__(16) char smem[68608];    // overlay region (~67KB)
  __shared__ float invS[32];
  float (*Stile)[32][260] =
      reinterpret_cast<float (*)[32][260]>(smem);            // phase 1
  unsigned short (*Ptile)[32][264] =
      reinterpret_cast<unsigned short (*)[32][264]>(smem);   // phase 3
  float (*Rtile)[32][68] =
      reinterpret_cast<float (*)[32][68]>(smem + 33792);     // phase 3

  const int tid = threadIdx.x, lane = tid & 63, wave = tid >> 6;
  const int l15 = lane & 15, quad = lane >> 4;
  const int bx = blockIdx.x;
  const int qb = (bx & 1) ? (63 - (bx >> 1)) : (bx >> 1);  // heavy+light mix
  const int h = blockIdx.y, q0 = qb * 32, col0 = h * CHD;
  const int g0 = q0 + wave;                   // wave's row in group A (0..15)
  const int g1 = q0 + 16 + wave;              // wave's row in group B (16..31)
  const int ntiles = (q0 + 287) >> 8;         // 256-col tiles covering 0..q0+31
  const int rmax = q0 + 31;                   // last valid column in this block

  // A-frags for both row groups: m=l15, k=kb*32+quad*8+j [m89/m91 layout]
  short8 a0h[2], a0l[2], a1h[2], a1l[2];
  {
    const size_t qbA = (size_t)(q0 + l15) * CD + col0 + quad * 8;
    const size_t qbB = (size_t)(q0 + 16 + l15) * CD + col0 + quad * 8;
#pragma unroll
    for (int kb = 0; kb < 2; kb++) {
      a0h[kb] = *reinterpret_cast<const short8*>(qh + qbA + kb * 32);
      a0l[kb] = *reinterpret_cast<const short8*>(ql + qbA + kb * 32);
      a1h[kb] = *reinterpret_cast<const short8*>(qh + qbB + kb * 32);
      a1l[kb] = *reinterpret_cast<const short8*>(ql + qbB + kb * 32);
    }
  }

  f32x32 s0, s1;
#pragma unroll
  for (int t = 0; t < 32; t++) { s0[t] = NEGS; s1[t] = NEGS; }

  // ---- Phase 1: scores (both row groups share the wave's K B-frag) ----
#pragma unroll
  for (int jt = 0; jt < 8; jt++) {
    if (jt < ntiles) {                        // WG-uniform
      const int j0 = jt * 256;
      const int buf = jt & 1;
      if (j0 + 16 * wave <= rmax) {           // wave-uniform causal-tail skip
        const size_t kbase = (size_t)(j0 + 16 * wave + l15) * CD + col0 + quad * 8;
        f32x4 c0 = {0.f, 0.f, 0.f, 0.f};
        f32x4 c1 = {0.f, 0.f, 0.f, 0.f};
#pragma unroll
        for (int kb = 0; kb < 2; kb++) {
          const short8 b_h = *reinterpret_cast<const short8*>(kh + kbase + kb * 32);
          const short8 b_l = *reinterpret_cast<const short8*>(kl + kbase + kb * 32);
          c0 = __builtin_amdgcn_mfma_f32_16x16x32_bf16(a0l[kb], b_l, c0, 0, 0, 0);
          c0 = __builtin_amdgcn_mfma_f32_16x16x32_bf16(a0h[kb], b_l, c0, 0, 0, 0);
          c0 = __builtin_amdgcn_mfma_f32_16x16x32_bf16(a0l[kb], b_h, c0, 0, 0, 0);
          c0 = __builtin_amdgcn_mfma_f32_16x16x32_bf16(a0h[kb], b_h, c0, 0, 0, 0);
          c1 = __builtin_amdgcn_mfma_f32_16x16x32_bf16(a1l[kb], b_l, c1, 0, 0, 0);
          c1 = __builtin_amdgcn_mfma_f32_16x16x32_bf16(a1h[kb], b_l, c1, 0, 0, 0);
          c1 = __builtin_amdgcn_mfma_f32_16x16x32_bf16(a1l[kb], b_h, c1, 0, 0, 0);
          c1 = __builtin_amdgcn_mfma_f32_16x16x32_bf16(a1h[kb], b_h, c1, 0, 0, 0);
        }
        // C layout: col(seq) = 16*wave + l15, row(q) = quad*4 + r (+16 for B)
#pragma unroll
        for (int r = 0; r < 4; r++) {
          Stile[buf][quad * 4 + r][16 * wave + l15] = c0[r];
          Stile[buf][16 + quad * 4 + r][16 * wave + l15] = c1[r];
        }
      }
      __syncthreads();
      // Gather MY rows: lane ll owns cols j0 + 64*tt + ll (2-way = free)
#pragma unroll
      for (int tt = 0; tt < 4; tt++) {
        const int col = j0 + 64 * tt + lane;
        if (j0 + 64 * tt <= g0) {             // wave-uniform group-valid check
          const float v = Stile[buf][wave][64 * tt + lane] * 0.125f;  // exact
          s0[jt * 4 + tt] = (col <= g0) ? v : NEGS;
        }
        if (j0 + 64 * tt <= g1) {
          const float v = Stile[buf][wave + 16][64 * tt + lane] * 0.125f;
          s1[jt * 4 + tt] = (col <= g1) ? v : NEGS;
        }
      }
      // no trailing barrier: next scatter targets the other buffer
    }
  }

  // ---- Phase 2: fused 2-row Michelot per wave (32 rows in parallel) ----
  float inv0, inv1;
  entmax_pair(s0, s1, g0, g1, inv0, inv1);
  if (lane == 0) { invS[wave] = inv0; invS[wave + 16] = inv1; }

  // Overlay lifetime fence: all waves' Stile reads (phase 1) complete before
  // any Ptile/Rtile write (phase 3) re-uses the same LDS bytes.
  __syncthreads();

  // ---- Phase 3: P @ V (wave = (kgroup, dim-block); both row groups) ----
  f32x4 acc0 = {0.f, 0.f, 0.f, 0.f};
  f32x4 acc1 = {0.f, 0.f, 0.f, 0.f};
  const int db = wave & 3, kcg = wave >> 2;
#pragma unroll
  for (int jt = 0; jt < 8; jt++) {
    if (jt < ntiles) {
      const int j0 = jt * 256;
      const int buf = jt & 1;
      // write MY rows' p for this tile (bf16; zeros where masked)
#pragma unroll
      for (int tt = 0; tt < 4; tt++)
        if (j0 + 64 * tt <= rmax) {           // skip groups no chunk reads
          Ptile[buf][wave][64 * tt + lane] = bf16_bits(s0[jt * 4 + tt]);
          Ptile[buf][wave + 16][64 * tt + lane] = bf16_bits(s1[jt * 4 + tt]);
        }
      __syncthreads();
      const size_t vrowbase =
          (size_t)(col0 + 16 * db + l15) * CL + j0;
#pragma unroll
      for (int t2 = 0; t2 < 2; t2++) {
        const int kc = 2 * kcg + t2;  // this wave's K-chunk of 32
        if (j0 + kc * 32 <= rmax) {           // wave-uniform causal-tail skip
          const short8 pa0 =
              *reinterpret_cast<const short8*>(&Ptile[buf][l15][kc * 32 + quad * 8]);
          const short8 pa1 =
              *reinterpret_cast<const short8*>(&Ptile[buf][l15 + 16][kc * 32 + quad * 8]);
          const size_t vb = vrowbase + kc * 32 + quad * 8;
          const short8 vbh = *reinterpret_cast<const short8*>(vhT + vb);
          const short8 vbl = *reinterpret_cast<const short8*>(vlT + vb);
          acc0 = __builtin_amdgcn_mfma_f32_16x16x32_bf16(pa0, vbl, acc0, 0, 0, 0);
          acc0 = __builtin_amdgcn_mfma_f32_16x16x32_bf16(pa0, vbh, acc0, 0, 0, 0);
          acc1 = __builtin_amdgcn_mfma_f32_16x16x32_bf16(pa1, vbl, acc1, 0, 0, 0);
          acc1 = __builtin_amdgcn_mfma_f32_16x16x32_bf16(pa1, vbh, acc1, 0, 0, 0);
        }
      }
      // no trailing barrier: next P-write targets the other buffer
    }
  }

  // ---- Cross-wave K-group reduce + epilogue (32 rows) ----
#pragma unroll
  for (int r = 0; r < 4; r++) {
    Rtile[kcg][quad * 4 + r][db * 16 + l15] = acc0[r];
    Rtile[kcg][16 + quad * 4 + r][db * 16 + l15] = acc1[r];
  }
  __syncthreads();
  if (wave < 4) {  // wave u handles dim-block u for all 32 rows
#pragma unroll
    for (int r = 0; r < 8; r++) {
      const int row = quad * 8 + r;
      float o = (Rtile[0][row][wave * 16 + l15] + Rtile[1][row][wave * 16 + l15]) +
                (Rtile[2][row][wave * 16 + l15] + Rtile[3][row][wave * 16 + l15]);
      o *= invS[row];
      short sh, sl;
      split1(o, sh, sl);
      const size_t oidx = (size_t)(q0 + row) * CD + col0 + wave * 16 + l15;
      oh[oidx] = sh;
      ol[oidx] = sl;
    }
  }
}

extern "C" void kernel_launch(void* const* d_in, const int* in_sizes, int n_in,
                              void* d_out, int out_size, void* d_ws, size_t ws_size,
                              hipStream_t stream) {
  const float* x  = (const float*)d_in[0];
  const float* Wq = (const float*)d_in[1];
  const float* Wk = (const float*)d_in[2];
  const float* Wv = (const float*)d_in[3];
  const float* Wo = (const float*)d_in[4];
  float* out = (float*)d_out;

  // Workspace layout (56 MB total)
  char* ws = (char*)d_ws;
  short* xh  = (short*)(ws + (0ull  << 20));
  short* xl  = (short*)(ws + (4ull  << 20));
  short* wqh = (short*)(ws + (8ull  << 20));
  short* wql = (short*)(ws + (10ull << 20));
  short* wkh = (short*)(ws + (12ull << 20));
  short* wkl = (short*)(ws + (14ull << 20));
  short* wvh = (short*)(ws + (16ull << 20));
  short* wvl = (short*)(ws + (18ull << 20));
  short* woh = (short*)(ws + (20ull << 20));
  short* wol = (short*)(ws + (22ull << 20));
  short* qhp = (short*)(ws + (24ull << 20));
  short* qlp = (short*)(ws + (28ull << 20));
  short* khp = (short*)(ws + (32ull << 20));
  short* klp = (short*)(ws + (36ull << 20));
  short* vhT = (short*)(ws + (40ull << 20));
  short* vlT = (short*)(ws + (44ull << 20));
  short* ohp = (short*)(ws + (48ull << 20));
  short* olp = (short*)(ws + (52ull << 20));

  split_all<<<6144, 256, 0, stream>>>(x, Wq, Wk, Wv, Wo,
                                      xh, xl, wqh, wql, wkh, wkl,
                                      wvh, wvl, woh, wol);

  // Fused QKV: grid.x = 24, sel = x>>3 -> q/k planes row-major, vT transposed
  gemm128_split<<<dim3(24, CL / 128), 256, 0, stream>>>(
      xh, xl, wqh, wql, wkh, wkl, wvh, wvl,
      qhp, qlp, khp, klp, vhT, vlT, nullptr, 0);

  attn32<<<dim3(CL / 32, CH), 1024, 0, stream>>>(
      qhp, qlp, khp, klp, vhT, vlT, ohp, olp);

  // Wo: grid.x = 8 (sel = 0), fp32 out
  gemm128_split<<<dim3(8, CL / 128), 256, 0, stream>>>(
      ohp, olp, woh, wol, woh, wol, woh, wol,
      ohp, olp, ohp, olp, ohp, olp, out, 1);
}